// Round 11
// baseline (177.172 us; speedup 1.0000x reference)
//
#include <hip/hip_runtime.h>
#include <hip/hip_bf16.h>
#include <stdint.h>

typedef __attribute__((ext_vector_type(8))) short short8;
typedef __attribute__((ext_vector_type(4))) float floatx4;

#define FEAT_DIM 1536
#define QD 64
#define NROWS 8192
#define TT 513

__device__ __forceinline__ unsigned short f2bf(float x) {
  union { float f; unsigned u; } t; t.f = x;
  unsigned r = t.u + 0x7fffu + ((t.u >> 16) & 1u);
  return (unsigned short)(r >> 16);
}
__device__ __forceinline__ float bf2f(unsigned short u) {
  union { float f; unsigned u; } t; t.u = ((unsigned)u) << 16;
  return t.f;
}
// monotone float->uint map (order-preserving), low 4 bits freed for an index
__device__ __forceinline__ unsigned packkey(float f, int idx) {
  unsigned x = __float_as_uint(f);
  unsigned m = (unsigned)((int)x >> 31);
  unsigned u = x ^ (m | 0x80000000u);
  return (u & ~15u) | (unsigned)idx;
}
__device__ __forceinline__ float unpackkey(unsigned u) {
  u &= ~15u;
  unsigned x = (u & 0x80000000u) ? (u ^ 0x80000000u) : ~u;
  return __uint_as_float(x);
}

// K1: sf = win @ proj (MFMA bf16), proj transposed+converted on the fly.
// Block 257 zero-inits psum/cnt2 for k_fin's cross-block tail.
__global__ __launch_bounds__(256, 4) void k_sf(const float* __restrict__ feat,
                                               const float* __restrict__ proj,
                                               unsigned short* __restrict__ sfb,
                                               float* __restrict__ sq,
                                               float* __restrict__ psum,
                                               unsigned* __restrict__ cnt2) {
  if (threadIdx.x == 0 && blockIdx.x == 0) { *psum = 0.0f; *cnt2 = 0u; }
  const int tid = threadIdx.x;
  const int wave = tid >> 6, lane = tid & 63;
  const int q = lane >> 4, n = lane & 15;
  const int rbase = blockIdx.x * 16;
  const int row = rbase + n;
  const int b = row >> 9, ti = row & 511;
  const float* fb = feat + (size_t)(b * TT + ti) * FEAT_DIM;
  const int kw = wave * 384;

  floatx4 acc0 = {0,0,0,0}, acc1 = {0,0,0,0}, acc2 = {0,0,0,0}, acc3 = {0,0,0,0};

  int koff = kw + q * 8;
  floatx4 f0 = *(const floatx4*)(fb + koff);
  floatx4 f1 = *(const floatx4*)(fb + koff + 4);
  floatx4 g0 = *(const floatx4*)(fb + FEAT_DIM + koff);
  floatx4 g1 = *(const floatx4*)(fb + FEAT_DIM + koff + 4);

  for (int ks = 0; ks < 12; ++ks) {
    floatx4 nf0, nf1, ng0, ng1;
    if (ks < 11) {
      int ko = kw + (ks + 1) * 32 + q * 8;
      nf0 = *(const floatx4*)(fb + ko);
      nf1 = *(const floatx4*)(fb + ko + 4);
      ng0 = *(const floatx4*)(fb + FEAT_DIM + ko);
      ng1 = *(const floatx4*)(fb + FEAT_DIM + ko + 4);
    }
    const float* pp = proj + (size_t)(kw + ks * 32 + q * 8) * QD + n;
    union { unsigned short u[8]; short8 v; } B0, B1, B2, B3;
#pragma unroll
    for (int j = 0; j < 8; ++j) {
      B0.u[j] = f2bf(pp[j * QD]);
      B1.u[j] = f2bf(pp[j * QD + 16]);
      B2.u[j] = f2bf(pp[j * QD + 32]);
      B3.u[j] = f2bf(pp[j * QD + 48]);
    }
    __builtin_amdgcn_sched_barrier(0);
    union { unsigned short u[8]; short8 v; } A;
#pragma unroll
    for (int j = 0; j < 4; ++j) A.u[j] = f2bf(0.5f * (f0[j] + g0[j]));
#pragma unroll
    for (int j = 0; j < 4; ++j) A.u[4 + j] = f2bf(0.5f * (f1[j] + g1[j]));
    acc0 = __builtin_amdgcn_mfma_f32_16x16x32_bf16(A.v, B0.v, acc0, 0, 0, 0);
    acc1 = __builtin_amdgcn_mfma_f32_16x16x32_bf16(A.v, B1.v, acc1, 0, 0, 0);
    acc2 = __builtin_amdgcn_mfma_f32_16x16x32_bf16(A.v, B2.v, acc2, 0, 0, 0);
    acc3 = __builtin_amdgcn_mfma_f32_16x16x32_bf16(A.v, B3.v, acc3, 0, 0, 0);
    if (ks < 11) { f0 = nf0; f1 = nf1; g0 = ng0; g1 = ng1; }
  }

  __shared__ float part[4][16][64];
#pragma unroll
  for (int r = 0; r < 4; ++r) {
    part[wave][q * 4 + r][0 * 16 + n] = acc0[r];
    part[wave][q * 4 + r][1 * 16 + n] = acc1[r];
    part[wave][q * 4 + r][2 * 16 + n] = acc2[r];
    part[wave][q * 4 + r][3 * 16 + n] = acc3[r];
  }
  __syncthreads();
  {
    const int r = tid >> 4;
    const int c0 = (tid & 15) * 4;
    float sqp = 0.0f;
    union { unsigned short u[4]; uint2 d; } P;
#pragma unroll
    for (int j = 0; j < 4; ++j) {
      float v = part[0][r][c0 + j] + part[1][r][c0 + j] +
                part[2][r][c0 + j] + part[3][r][c0 + j];
      P.u[j] = f2bf(v);
      float bv = bf2f(P.u[j]);
      sqp += bv * bv;
    }
    *(uint2*)(sfb + (size_t)(rbase + r) * QD + c0) = P.d;
#pragma unroll
    for (int off = 1; off < 16; off <<= 1) sqp += __shfl_xor(sqp, off, 64);
    if ((tid & 15) == 0) sq[rbase + r] = sqp;
  }
}

// K2: byte-identical to R9's measured-59.5us k_knn. Pure producer -> tops.
__global__ __launch_bounds__(256, 4) void k_knn(const unsigned short* __restrict__ sfb,
                                                const float* __restrict__ sq,
                                                float* __restrict__ tops) {
  const int tid = threadIdx.x;
  const int wave = tid >> 6, lane = tid & 63;
  const int q = lane >> 4, n = lane & 15;
  const int ib = (blockIdx.x >> 2) * 32;
  const int js = blockIdx.x & 3;
  const short8* sfv = (const short8*)sfb;

  short8 b0 = sfv[(ib + n) * 8 + q];
  short8 b1 = sfv[(ib + n) * 8 + 4 + q];
  short8 b2 = sfv[(ib + 16 + n) * 8 + q];
  short8 b3 = sfv[(ib + 16 + n) * 8 + 4 + q];

  float lst0[16], lst1[16];
#pragma unroll
  for (int k = 0; k < 16; ++k) { lst0[k] = 3.0e38f; lst1[k] = 3.0e38f; }

  const int j0 = js * 2048 + wave * 512;
  short8 A0 = sfv[(j0 + n) * 8 + q];
  short8 A1 = sfv[(j0 + n) * 8 + 4 + q];
  floatx4 s4 = *(const floatx4*)(sq + j0 + q * 4);

  for (int jt = 0; jt < 512; jt += 16) {
    const int jn = j0 + jt + 16;   // final prefetch overruns into ws scratch: harmless
    short8 nA0 = sfv[(jn + n) * 8 + q];
    short8 nA1 = sfv[(jn + n) * 8 + 4 + q];
    floatx4 ns4 = *(const floatx4*)(sq + jn + q * 4);
    __builtin_amdgcn_sched_barrier(0);

    floatx4 acc0 = {0, 0, 0, 0};
    acc0 = __builtin_amdgcn_mfma_f32_16x16x32_bf16(A0, b0, acc0, 0, 0, 0);
    acc0 = __builtin_amdgcn_mfma_f32_16x16x32_bf16(A1, b1, acc0, 0, 0, 0);
    floatx4 acc1 = {0, 0, 0, 0};
    acc1 = __builtin_amdgcn_mfma_f32_16x16x32_bf16(A0, b2, acc1, 0, 0, 0);
    acc1 = __builtin_amdgcn_mfma_f32_16x16x32_bf16(A1, b3, acc1, 0, 0, 0);

#pragma unroll
    for (int r = 0; r < 4; ++r) {
      float c = fmaf(-2.0f, acc0[r], s4[r]);   // key = sq_j - 2*dot
#pragma unroll
      for (int k = 15; k >= 1; --k)
        lst0[k] = __builtin_amdgcn_fmed3f(lst0[k], lst0[k - 1], c);
      lst0[0] = fminf(lst0[0], c);
    }
#pragma unroll
    for (int r = 0; r < 4; ++r) {
      float c = fmaf(-2.0f, acc1[r], s4[r]);
#pragma unroll
      for (int k = 15; k >= 1; --k)
        lst1[k] = __builtin_amdgcn_fmed3f(lst1[k], lst1[k - 1], c);
      lst1[0] = fminf(lst1[0], c);
    }
    A0 = nA0; A1 = nA1; s4 = ns4;
  }

  __shared__ unsigned lists[16 * 547];
  const int sl = wave * 4 + q;
#pragma unroll
  for (int k = 0; k < 16; ++k) {
    lists[sl * 547 + n * 17 + k] = packkey(lst0[k], sl);
    lists[sl * 547 + (n + 16) * 17 + k] = packkey(lst1[k], sl);
  }
  __syncthreads();

  const int sub = lane & 15;
#pragma unroll 1
  for (int pass = 0; pass < 2; ++pass) {
    const int rr = pass * 16 + wave * 4 + (lane >> 4);   // 0..31
    int p = 0;
    unsigned h = lists[sub * 547 + rr * 17];
    float* trow = tops + ((size_t)(ib + rr) * 4 + js) * 16;
#pragma unroll 1
    for (int it = 0; it < 16; ++it) {
      unsigned u = h;
#pragma unroll
      for (int off = 1; off < 16; off <<= 1) {
        unsigned u2 = __shfl_xor(u, off, 64);
        u = (u2 < u) ? u2 : u;
      }
      if (sub == 0) trow[it] = unpackkey(u);
      if ((u & 15u) == (unsigned)sub) { ++p; h = lists[sub * 547 + rr * 17 + p]; }
    }
  }
}

// K3 (fused merge+final): grid 32. Per-thread 4-way merge of 4 sorted segments
// -> sqrt-sum -> intrew (agent write-through, 32KB total). Last-of-32 block
// applies StreamNorm + reward add. Fence-free: relaxed agent atomics only
// (R8 lesson: device fences thrash L2; R10 lesson: keep write-through tiny).
__global__ __launch_bounds__(256) void k_fin(const float* __restrict__ tops,
                                             const float* __restrict__ sq,
                                             float* __restrict__ intrew,
                                             float* __restrict__ psum,
                                             unsigned* __restrict__ cnt2,
                                             const float* __restrict__ reward,
                                             float* __restrict__ out) {
  const int tid = threadIdx.x;
  __shared__ float buf[256][65];
  const size_t base = (size_t)blockIdx.x * 256 * 64;
#pragma unroll 1
  for (int j = 0; j < 64; ++j) {
    int f = j * 256 + tid;
    buf[f >> 6][f & 63] = tops[base + f];
  }
  __syncthreads();

  const int row = blockIdx.x * 256 + tid;
  const float sqr = sq[row];
  int c0 = 1, c1 = 17, c2 = 33, c3 = 49;
  float h0 = buf[tid][0], h1 = buf[tid][16], h2 = buf[tid][32], h3 = buf[tid][48];
  float sum = 0.0f;
#pragma unroll 1
  for (int it = 0; it < 16; ++it) {
    float m = fminf(fminf(h0, h1), fminf(h2, h3));
    sum += sqrtf(fmaxf(sqr + m, 1e-12f));
    if (m == h0)      { h0 = (c0 < 16) ? buf[tid][c0] : 3.0e38f; ++c0; }
    else if (m == h1) { h1 = (c1 < 32) ? buf[tid][c1] : 3.0e38f; ++c1; }
    else if (m == h2) { h2 = (c2 < 48) ? buf[tid][c2] : 3.0e38f; ++c2; }
    else              { h3 = (c3 < 64) ? buf[tid][c3] : 3.0e38f; ++c3; }
  }
  float ir = sum * (1.0f / 16.0f);
  __hip_atomic_store(&intrew[row], ir, __ATOMIC_RELAXED, __HIP_MEMORY_SCOPE_AGENT);

  float w = ir;
#pragma unroll
  for (int off = 1; off < 64; off <<= 1) w += __shfl_xor(w, off, 64);
  __shared__ float ws4[4];
  if ((tid & 63) == 0) ws4[tid >> 6] = w;
  __syncthreads();                 // also drains each wave's intrew stores (vmcnt)
  __shared__ unsigned olds;
  if (tid == 0) {
    float s = ws4[0] + ws4[1] + ws4[2] + ws4[3];
    __hip_atomic_fetch_add(psum, s, __ATOMIC_RELAXED, __HIP_MEMORY_SCOPE_AGENT);
    asm volatile("s_waitcnt vmcnt(0)" ::: "memory");
    olds = __hip_atomic_fetch_add(cnt2, 1u, __ATOMIC_RELAXED, __HIP_MEMORY_SCOPE_AGENT);
  }
  __syncthreads();
  if (olds != 31u) return;

  // finisher: StreamNorm + reward add over all rows
  float total = __hip_atomic_load(psum, __ATOMIC_RELAXED, __HIP_MEMORY_SCOPE_AGENT);
  float mean = total * (1.0f / 8192.0f);
  float mag = 0.99f + 0.01f * mean;
  float inv = 1.0f / (mag + 1e-8f);
#pragma unroll 1
  for (int i = tid; i < NROWS; i += 256) {
    float ir2 = __hip_atomic_load(&intrew[i], __ATOMIC_RELAXED, __HIP_MEMORY_SCOPE_AGENT);
    int b = i >> 9, ti = i & 511;
    out[i] = reward[b * TT + ti] + ir2 * inv;
  }
}

extern "C" void kernel_launch(void* const* d_in, const int* in_sizes, int n_in,
                              void* d_out, int out_size, void* d_ws, size_t ws_size,
                              hipStream_t stream) {
  const float* feat   = (const float*)d_in[0];
  const float* reward = (const float*)d_in[1];
  const float* proj   = (const float*)d_in[2];
  float* out = (float*)d_out;

  char* ws = (char*)d_ws;
  unsigned short* sfb = (unsigned short*)ws;                   // 1 MB: sf bf16 [8192][64]
  float* sq           = (float*)(ws + 0x100000);               // 32 KB
  float* intrew       = (float*)(ws + 0x110000);               // 32 KB
  float* psum         = (float*)(ws + 0x120000);               // 4 B
  unsigned* cnt2      = (unsigned*)(ws + 0x120040);            // 4 B
  float* tops         = (float*)(ws + 0x160000);               // 2 MB: [8192][4][16]

  k_sf<<<512, 256, 0, stream>>>(feat, proj, sfb, sq, psum, cnt2);
  k_knn<<<1024, 256, 0, stream>>>(sfb, sq, tops);
  k_fin<<<32, 256, 0, stream>>>(tops, sq, intrew, psum, cnt2, reward, out);
}

// Round 13
// 156.686 us; speedup vs baseline: 1.1307x; 1.1307x over previous
//
#include <hip/hip_runtime.h>
#include <hip/hip_bf16.h>
#include <stdint.h>

typedef __attribute__((ext_vector_type(8))) short short8;
typedef __attribute__((ext_vector_type(4))) float floatx4;

#define FEAT_DIM 1536
#define QD 64
#define NROWS 8192
#define TT 513

__device__ __forceinline__ unsigned short f2bf(float x) {
  union { float f; unsigned u; } t; t.f = x;
  unsigned r = t.u + 0x7fffu + ((t.u >> 16) & 1u);
  return (unsigned short)(r >> 16);
}
__device__ __forceinline__ float bf2f(unsigned short u) {
  union { float f; unsigned u; } t; t.u = ((unsigned)u) << 16;
  return t.f;
}
// monotone float->uint map (order-preserving), low 4 bits freed for an index
__device__ __forceinline__ unsigned packkey(float f, int idx) {
  unsigned x = __float_as_uint(f);
  unsigned m = (unsigned)((int)x >> 31);
  unsigned u = x ^ (m | 0x80000000u);
  return (u & ~15u) | (unsigned)idx;
}
__device__ __forceinline__ float unpackkey(unsigned u) {
  u &= ~15u;
  unsigned x = (u & 0x80000000u) ? (u ^ 0x80000000u) : ~u;
  return __uint_as_float(x);
}

// K1: sf = win @ proj (MFMA bf16), proj transposed+converted on the fly.
// (byte-identical to R9's k_sf)
__global__ __launch_bounds__(256, 4) void k_sf(const float* __restrict__ feat,
                                               const float* __restrict__ proj,
                                               unsigned short* __restrict__ sfb,
                                               float* __restrict__ sq) {
  const int tid = threadIdx.x;
  const int wave = tid >> 6, lane = tid & 63;
  const int q = lane >> 4, n = lane & 15;
  const int rbase = blockIdx.x * 16;
  const int row = rbase + n;
  const int b = row >> 9, ti = row & 511;
  const float* fb = feat + (size_t)(b * TT + ti) * FEAT_DIM;
  const int kw = wave * 384;

  floatx4 acc0 = {0,0,0,0}, acc1 = {0,0,0,0}, acc2 = {0,0,0,0}, acc3 = {0,0,0,0};

  int koff = kw + q * 8;
  floatx4 f0 = *(const floatx4*)(fb + koff);
  floatx4 f1 = *(const floatx4*)(fb + koff + 4);
  floatx4 g0 = *(const floatx4*)(fb + FEAT_DIM + koff);
  floatx4 g1 = *(const floatx4*)(fb + FEAT_DIM + koff + 4);

  for (int ks = 0; ks < 12; ++ks) {
    floatx4 nf0, nf1, ng0, ng1;
    if (ks < 11) {
      int ko = kw + (ks + 1) * 32 + q * 8;
      nf0 = *(const floatx4*)(fb + ko);
      nf1 = *(const floatx4*)(fb + ko + 4);
      ng0 = *(const floatx4*)(fb + FEAT_DIM + ko);
      ng1 = *(const floatx4*)(fb + FEAT_DIM + ko + 4);
    }
    const float* pp = proj + (size_t)(kw + ks * 32 + q * 8) * QD + n;
    union { unsigned short u[8]; short8 v; } B0, B1, B2, B3;
#pragma unroll
    for (int j = 0; j < 8; ++j) {
      B0.u[j] = f2bf(pp[j * QD]);
      B1.u[j] = f2bf(pp[j * QD + 16]);
      B2.u[j] = f2bf(pp[j * QD + 32]);
      B3.u[j] = f2bf(pp[j * QD + 48]);
    }
    __builtin_amdgcn_sched_barrier(0);
    union { unsigned short u[8]; short8 v; } A;
#pragma unroll
    for (int j = 0; j < 4; ++j) A.u[j] = f2bf(0.5f * (f0[j] + g0[j]));
#pragma unroll
    for (int j = 0; j < 4; ++j) A.u[4 + j] = f2bf(0.5f * (f1[j] + g1[j]));
    acc0 = __builtin_amdgcn_mfma_f32_16x16x32_bf16(A.v, B0.v, acc0, 0, 0, 0);
    acc1 = __builtin_amdgcn_mfma_f32_16x16x32_bf16(A.v, B1.v, acc1, 0, 0, 0);
    acc2 = __builtin_amdgcn_mfma_f32_16x16x32_bf16(A.v, B2.v, acc2, 0, 0, 0);
    acc3 = __builtin_amdgcn_mfma_f32_16x16x32_bf16(A.v, B3.v, acc3, 0, 0, 0);
    if (ks < 11) { f0 = nf0; f1 = nf1; g0 = ng0; g1 = ng1; }
  }

  __shared__ float part[4][16][64];
#pragma unroll
  for (int r = 0; r < 4; ++r) {
    part[wave][q * 4 + r][0 * 16 + n] = acc0[r];
    part[wave][q * 4 + r][1 * 16 + n] = acc1[r];
    part[wave][q * 4 + r][2 * 16 + n] = acc2[r];
    part[wave][q * 4 + r][3 * 16 + n] = acc3[r];
  }
  __syncthreads();
  {
    const int r = tid >> 4;
    const int c0 = (tid & 15) * 4;
    float sqp = 0.0f;
    union { unsigned short u[4]; uint2 d; } P;
#pragma unroll
    for (int j = 0; j < 4; ++j) {
      float v = part[0][r][c0 + j] + part[1][r][c0 + j] +
                part[2][r][c0 + j] + part[3][r][c0 + j];
      P.u[j] = f2bf(v);
      float bv = bf2f(P.u[j]);
      sqp += bv * bv;
    }
    *(uint2*)(sfb + (size_t)(rbase + r) * QD + c0) = P.d;
#pragma unroll
    for (int off = 1; off < 16; off <<= 1) sqp += __shfl_xor(sqp, off, 64);
    if ((tid & 15) == 0) sq[rbase + r] = sqp;
  }
}

// K2: byte-identical to R9's measured-59.5us k_knn. Pure producer -> tops.
__global__ __launch_bounds__(256, 4) void k_knn(const unsigned short* __restrict__ sfb,
                                                const float* __restrict__ sq,
                                                float* __restrict__ tops) {
  const int tid = threadIdx.x;
  const int wave = tid >> 6, lane = tid & 63;
  const int q = lane >> 4, n = lane & 15;
  const int ib = (blockIdx.x >> 2) * 32;
  const int js = blockIdx.x & 3;
  const short8* sfv = (const short8*)sfb;

  short8 b0 = sfv[(ib + n) * 8 + q];
  short8 b1 = sfv[(ib + n) * 8 + 4 + q];
  short8 b2 = sfv[(ib + 16 + n) * 8 + q];
  short8 b3 = sfv[(ib + 16 + n) * 8 + 4 + q];

  float lst0[16], lst1[16];
#pragma unroll
  for (int k = 0; k < 16; ++k) { lst0[k] = 3.0e38f; lst1[k] = 3.0e38f; }

  const int j0 = js * 2048 + wave * 512;
  short8 A0 = sfv[(j0 + n) * 8 + q];
  short8 A1 = sfv[(j0 + n) * 8 + 4 + q];
  floatx4 s4 = *(const floatx4*)(sq + j0 + q * 4);

  for (int jt = 0; jt < 512; jt += 16) {
    const int jn = j0 + jt + 16;   // final prefetch overruns into ws scratch: harmless
    short8 nA0 = sfv[(jn + n) * 8 + q];
    short8 nA1 = sfv[(jn + n) * 8 + 4 + q];
    floatx4 ns4 = *(const floatx4*)(sq + jn + q * 4);
    __builtin_amdgcn_sched_barrier(0);

    floatx4 acc0 = {0, 0, 0, 0};
    acc0 = __builtin_amdgcn_mfma_f32_16x16x32_bf16(A0, b0, acc0, 0, 0, 0);
    acc0 = __builtin_amdgcn_mfma_f32_16x16x32_bf16(A1, b1, acc0, 0, 0, 0);
    floatx4 acc1 = {0, 0, 0, 0};
    acc1 = __builtin_amdgcn_mfma_f32_16x16x32_bf16(A0, b2, acc1, 0, 0, 0);
    acc1 = __builtin_amdgcn_mfma_f32_16x16x32_bf16(A1, b3, acc1, 0, 0, 0);

#pragma unroll
    for (int r = 0; r < 4; ++r) {
      float c = fmaf(-2.0f, acc0[r], s4[r]);   // key = sq_j - 2*dot
#pragma unroll
      for (int k = 15; k >= 1; --k)
        lst0[k] = __builtin_amdgcn_fmed3f(lst0[k], lst0[k - 1], c);
      lst0[0] = fminf(lst0[0], c);
    }
#pragma unroll
    for (int r = 0; r < 4; ++r) {
      float c = fmaf(-2.0f, acc1[r], s4[r]);
#pragma unroll
      for (int k = 15; k >= 1; --k)
        lst1[k] = __builtin_amdgcn_fmed3f(lst1[k], lst1[k - 1], c);
      lst1[0] = fminf(lst1[0], c);
    }
    A0 = nA0; A1 = nA1; s4 = ns4;
  }

  __shared__ unsigned lists[16 * 547];
  const int sl = wave * 4 + q;
#pragma unroll
  for (int k = 0; k < 16; ++k) {
    lists[sl * 547 + n * 17 + k] = packkey(lst0[k], sl);
    lists[sl * 547 + (n + 16) * 17 + k] = packkey(lst1[k], sl);
  }
  __syncthreads();

  const int sub = lane & 15;
#pragma unroll 1
  for (int pass = 0; pass < 2; ++pass) {
    const int rr = pass * 16 + wave * 4 + (lane >> 4);   // 0..31
    int p = 0;
    unsigned h = lists[sub * 547 + rr * 17];
    float* trow = tops + ((size_t)(ib + rr) * 4 + js) * 16;
#pragma unroll 1
    for (int it = 0; it < 16; ++it) {
      unsigned u = h;
#pragma unroll
      for (int off = 1; off < 16; off <<= 1) {
        unsigned u2 = __shfl_xor(u, off, 64);
        u = (u2 < u) ? u2 : u;
      }
      if (sub == 0) trow[it] = unpackkey(u);
      if ((u & 15u) == (unsigned)sub) { ++p; h = lists[sub * 547 + rr * 17 + p]; }
    }
  }
}

// K2b: RE-GRIDDED merge. 256 blocks x 32 rows (R9's grid-32 version was the
// hidden ~55us hog: 1 block per 8 CUs + unroll-1 scalar staging = serialized
// HBM latency). float4 staging: 512 vector loads spread over 256 threads.
__global__ __launch_bounds__(256) void k_merge(const float* __restrict__ tops,
                                               const float* __restrict__ sq,
                                               float* __restrict__ intrew,
                                               float* __restrict__ psum) {
  const int tid = threadIdx.x;
  __shared__ float buf[32][68];
  const int ib = blockIdx.x * 32;
  const floatx4* tv = (const floatx4*)(tops + (size_t)ib * 64);
#pragma unroll
  for (int k = 0; k < 2; ++k) {
    int f4 = k * 256 + tid;                  // 0..511 (32 rows x 16 float4)
    floatx4 v = tv[f4];
    int r = f4 >> 4, c = (f4 & 15) * 4;
    *(floatx4*)(&buf[r][c]) = v;
  }
  __syncthreads();
  __shared__ float rsum[1];
  if (tid < 32) {
    const float* bb = buf[tid];
    const int row = ib + tid;
    const float sqr = sq[row];
    int c0 = 1, c1 = 17, c2 = 33, c3 = 49;
    float h0 = bb[0], h1 = bb[16], h2 = bb[32], h3 = bb[48];
    float sum = 0.0f;
#pragma unroll 1
    for (int it = 0; it < 16; ++it) {
      float m = fminf(fminf(h0, h1), fminf(h2, h3));
      sum += sqrtf(fmaxf(sqr + m, 1e-12f));
      if (m == h0)      { h0 = (c0 < 16) ? bb[c0] : 3.0e38f; ++c0; }
      else if (m == h1) { h1 = (c1 < 32) ? bb[c1] : 3.0e38f; ++c1; }
      else if (m == h2) { h2 = (c2 < 48) ? bb[c2] : 3.0e38f; ++c2; }
      else              { h3 = (c3 < 64) ? bb[c3] : 3.0e38f; ++c3; }
    }
    float ir = sum * (1.0f / 16.0f);
    intrew[row] = ir;
    float w = ir;
#pragma unroll
    for (int off = 1; off < 32; off <<= 1) w += __shfl_xor(w, off, 64);
    if (tid == 0) rsum[0] = w;
  }
  __syncthreads();
  if (tid == 0) psum[blockIdx.x] = rsum[0];
}

// K3: StreamNorm + add reward (psum has 256 block sums; shuffle+LDS reduce)
__global__ __launch_bounds__(256) void k_final(const float* __restrict__ reward,
                                               const float* __restrict__ intrew,
                                               const float* __restrict__ psum,
                                               float* __restrict__ out) {
  const int tid = threadIdx.x;
  const int wave = tid >> 6, lane = tid & 63;
  float v = psum[tid];                       // 256 entries
#pragma unroll
  for (int off = 1; off < 64; off <<= 1) v += __shfl_xor(v, off, 64);
  __shared__ float ws4[4];
  if (lane == 0) ws4[wave] = v;
  __syncthreads();
  float total = ws4[0] + ws4[1] + ws4[2] + ws4[3];
  float mean = total * (1.0f / 8192.0f);
  float mag = 0.99f + 0.01f * mean;
  float inv = 1.0f / (mag + 1e-8f);
  int i = blockIdx.x * 256 + tid;            // 0..8191
  int b = i >> 9, ti = i & 511;
  out[i] = reward[b * TT + ti] + intrew[i] * inv;
}

extern "C" void kernel_launch(void* const* d_in, const int* in_sizes, int n_in,
                              void* d_out, int out_size, void* d_ws, size_t ws_size,
                              hipStream_t stream) {
  const float* feat   = (const float*)d_in[0];
  const float* reward = (const float*)d_in[1];
  const float* proj   = (const float*)d_in[2];
  float* out = (float*)d_out;

  char* ws = (char*)d_ws;
  unsigned short* sfb = (unsigned short*)ws;                   // 1 MB: sf bf16 [8192][64]
  float* sq           = (float*)(ws + 0x100000);               // 32 KB
  float* intrew       = (float*)(ws + 0x110000);               // 32 KB
  float* psum         = (float*)(ws + 0x120000);               // 1 KB (256 floats)
  float* tops         = (float*)(ws + 0x160000);               // 2 MB: [8192][4][16]

  k_sf<<<512, 256, 0, stream>>>(feat, proj, sfb, sq);
  k_knn<<<1024, 256, 0, stream>>>(sfb, sq, tops);
  k_merge<<<256, 256, 0, stream>>>(tops, sq, intrew, psum);
  k_final<<<32, 256, 0, stream>>>(reward, intrew, psum, out);
}